// Round 1
// baseline (2338.154 us; speedup 1.0000x reference)
//
#include <hip/hip_runtime.h>

#define N_NODES 50000
#define N_EDGES 800000
#define N_GRAPHS 64
#define INDIM 128
#define HID 256
#define OUTD 10

// ---------------- CSR build ----------------
__global__ void k_hist(const int* __restrict__ dst, int* __restrict__ deg) {
  int e = blockIdx.x * blockDim.x + threadIdx.x;
  if (e < N_EDGES) atomicAdd(&deg[dst[e]], 1);
}

__global__ __launch_bounds__(1024) void k_scan(const int* __restrict__ deg,
                                               int* __restrict__ rowptr,
                                               int* __restrict__ cursor) {
  __shared__ int part[1024];
  const int n = N_NODES;
  const int per = (n + 1023) / 1024;
  int tid = threadIdx.x;
  int base = tid * per;
  int s = 0;
  for (int i = 0; i < per; ++i) {
    int idx = base + i;
    if (idx < n) s += deg[idx];
  }
  part[tid] = s;
  __syncthreads();
  for (int off = 1; off < 1024; off <<= 1) {
    int v = (tid >= off) ? part[tid - off] : 0;
    __syncthreads();
    part[tid] += v;
    __syncthreads();
  }
  int run = (tid == 0) ? 0 : part[tid - 1];
  for (int i = 0; i < per; ++i) {
    int idx = base + i;
    if (idx < n) {
      rowptr[idx] = run;
      cursor[idx] = run;
      run += deg[idx];
    }
  }
  if (tid == 0) rowptr[n] = part[1023];
}

__global__ void k_scatter(const int* __restrict__ src, const int* __restrict__ dst,
                          int* __restrict__ cursor, int* __restrict__ csr) {
  int e = blockIdx.x * blockDim.x + threadIdx.x;
  if (e < N_EDGES) {
    int pos = atomicAdd(&cursor[dst[e]], 1);
    csr[pos] = src[e];
  }
}

// ---------------- SpMM: out[n] = h[n] + sum_{e: dst=n} h[src[e]] ----------------
template <int DIM>
__global__ void k_spmm(const float* __restrict__ h, const int* __restrict__ rowptr,
                       const int* __restrict__ csr, float* __restrict__ out) {
  int node = blockIdx.x;
  int c = threadIdx.x;
  float acc = h[(size_t)node * DIM + c];
  int b = rowptr[node], e = rowptr[node + 1];
  for (int i = b; i < e; ++i) {
    int s = csr[i];
    acc += h[(size_t)s * DIM + c];
  }
  out[(size_t)node * DIM + c] = acc;
}

// ---------------- f32 tiled GEMM: C[M][256] = A[M][K] @ W[K][256] + bias ----------------
template <int K>
__global__ __launch_bounds__(256) void k_gemm(const float* __restrict__ A,
                                              const float* __restrict__ W,
                                              const float* __restrict__ bias,
                                              float* __restrict__ C, int M) {
  __shared__ float As[16][68];  // transposed tile: As[k][row]
  __shared__ float Bs[16][68];  // Bs[k][col]
  int tid = threadIdx.x;
  int tx = tid & 15, ty = tid >> 4;
  int rowBase = blockIdx.x * 64;
  int colBase = blockIdx.y * 64;
  float acc[4][4] = {};
  for (int kt = 0; kt < K / 16; ++kt) {
    int a_k = tid & 15;
    int a_r = tid >> 4;  // 0..15
#pragma unroll
    for (int i = 0; i < 4; ++i) {
      int row = a_r + i * 16;
      int grow = rowBase + row;
      float v = (grow < M) ? A[(size_t)grow * K + kt * 16 + a_k] : 0.0f;
      As[a_k][row] = v;
    }
    int b_c = tid & 63;
    int b_k0 = tid >> 6;  // 0..3
#pragma unroll
    for (int i = 0; i < 4; ++i) {
      int k = b_k0 + i * 4;
      Bs[k][b_c] = W[(size_t)(kt * 16 + k) * HID + colBase + b_c];
    }
    __syncthreads();
#pragma unroll
    for (int kk = 0; kk < 16; ++kk) {
      float4 av = *(const float4*)&As[kk][ty * 4];
      float4 bv = *(const float4*)&Bs[kk][tx * 4];
      float a[4] = {av.x, av.y, av.z, av.w};
      float b[4] = {bv.x, bv.y, bv.z, bv.w};
#pragma unroll
      for (int i = 0; i < 4; ++i)
#pragma unroll
        for (int j = 0; j < 4; ++j) acc[i][j] += a[i] * b[j];
    }
    __syncthreads();
  }
#pragma unroll
  for (int i = 0; i < 4; ++i) {
    int grow = rowBase + ty * 4 + i;
    if (grow < M) {
#pragma unroll
      for (int j = 0; j < 4; ++j) {
        int gcol = colBase + tx * 4 + j;
        C[(size_t)grow * HID + gcol] = acc[i][j] + bias[gcol];
      }
    }
  }
}

// ---------------- BN column stats (sum, sumsq) ----------------
__global__ void k_colstats(const float* __restrict__ X, float* __restrict__ st, int M) {
  int c = threadIdx.x;  // 256 threads = one per column
  float s = 0.f, s2 = 0.f;
  for (int r = blockIdx.x; r < M; r += gridDim.x) {
    float v = X[(size_t)r * HID + c];
    s += v;
    s2 += v * v;
  }
  atomicAdd(&st[c], s);
  atomicAdd(&st[HID + c], s2);
}

// ---------------- BN apply + ReLU (in place) ----------------
__global__ void k_bn_relu(float* __restrict__ X, const float* __restrict__ st,
                          const float* __restrict__ g, const float* __restrict__ b) {
  size_t i = (size_t)blockIdx.x * blockDim.x + threadIdx.x;
  if (i >= (size_t)N_NODES * HID) return;
  int c = (int)(i & (HID - 1));
  const float invM = 1.0f / N_NODES;
  float mean = st[c] * invM;
  float var = st[HID + c] * invM - mean * mean;
  float sc = g[c] * rsqrtf(var + 1e-5f);
  float sh = b[c] - mean * sc;
  float v = X[i] * sc + sh;
  X[i] = v > 0.f ? v : 0.f;
}

// ---------------- graph sum-pool (graph_id sorted) ----------------
template <int DIM>
__global__ void k_pool(const float* __restrict__ H, const int* __restrict__ gid,
                       float* __restrict__ gp) {
  const int CHUNK = 128;
  int base = blockIdx.x * CHUNK;
  int c = threadIdx.x;
  int end = base + CHUNK;
  if (end > N_NODES) end = N_NODES;
  int cur = gid[base];
  float acc = 0.f;
  for (int r = base; r < end; ++r) {
    int g = gid[r];
    if (g != cur) {
      atomicAdd(&gp[(size_t)cur * DIM + c], acc);
      acc = 0.f;
      cur = g;
    }
    acc += H[(size_t)r * DIM + c];
  }
  atomicAdd(&gp[(size_t)cur * DIM + c], acc);
}

// ---------------- final prediction heads ----------------
__global__ __launch_bounds__(256) void k_score(const float* __restrict__ gp0,
                                               const float* __restrict__ gp,
                                               const float* __restrict__ pw0,
                                               const float* __restrict__ pb0,
                                               const float* __restrict__ pw,
                                               const float* __restrict__ pb,
                                               float* __restrict__ out) {
  __shared__ float red[256];
  int g = blockIdx.x;
  int tid = threadIdx.x;
  for (int o = 0; o < OUTD; ++o) {
    float p = 0.f;
    if (tid < INDIM) p += gp0[g * INDIM + tid] * pw0[tid * OUTD + o];
#pragma unroll
    for (int l = 0; l < 4; ++l)
      p += gp[((size_t)l * N_GRAPHS + g) * HID + tid] * pw[(size_t)(l * HID + tid) * OUTD + o];
    red[tid] = p;
    __syncthreads();
    for (int s = 128; s > 0; s >>= 1) {
      if (tid < s) red[tid] += red[tid + s];
      __syncthreads();
    }
    if (tid == 0) {
      float r = red[0] + pb0[o];
      for (int l = 0; l < 4; ++l) r += pb[l * OUTD + o];
      out[g * OUTD + o] = r;
    }
    __syncthreads();
  }
}

extern "C" void kernel_launch(void* const* d_in, const int* in_sizes, int n_in,
                              void* d_out, int out_size, void* d_ws, size_t ws_size,
                              hipStream_t stream) {
  (void)in_sizes; (void)n_in; (void)out_size; (void)ws_size;
  const float* x = (const float*)d_in[0];
  const float* mlp0_w1 = (const float*)d_in[1];
  const float* mlp0_b1 = (const float*)d_in[2];
  const float* mlp0_bng = (const float*)d_in[3];
  const float* mlp0_bnb = (const float*)d_in[4];
  const float* mlp0_w2 = (const float*)d_in[5];
  const float* mlp0_b2 = (const float*)d_in[6];
  const float* mlps_w1 = (const float*)d_in[7];
  const float* mlps_b1 = (const float*)d_in[8];
  const float* mlps_bng = (const float*)d_in[9];
  const float* mlps_bnb = (const float*)d_in[10];
  const float* mlps_w2 = (const float*)d_in[11];
  const float* mlps_b2 = (const float*)d_in[12];
  const float* bng = (const float*)d_in[13];
  const float* bnb = (const float*)d_in[14];
  const float* pw0 = (const float*)d_in[15];
  const float* pb0 = (const float*)d_in[16];
  const float* pw = (const float*)d_in[17];
  const float* pb = (const float*)d_in[18];
  const int* eidx = (const int*)d_in[19];
  const int* gid = (const int*)d_in[20];
  const int* esrc = eidx;
  const int* edst = eidx + N_EDGES;

  char* w = (char*)d_ws;
  size_t off = 0;
  auto take = [&](size_t bytes) -> void* {
    void* p = w + off;
    off += (bytes + 255) & ~(size_t)255;
    return p;
  };
  float* bufA = (float*)take((size_t)N_NODES * HID * 4);
  float* bufB = (float*)take((size_t)N_NODES * HID * 4);
  int* deg = (int*)take((size_t)N_NODES * 4);
  int* rowptr = (int*)take((size_t)(N_NODES + 1) * 4);
  int* cursor = (int*)take((size_t)N_NODES * 4);
  int* csr = (int*)take((size_t)N_EDGES * 4);
  float* stats = (float*)take(8 * 512 * 4);
  float* gp0 = (float*)take((size_t)N_GRAPHS * INDIM * 4);
  float* gp = (float*)take((size_t)4 * N_GRAPHS * HID * 4);

  hipMemsetAsync(deg, 0, (size_t)N_NODES * 4, stream);
  hipMemsetAsync(stats, 0, 8 * 512 * 4, stream);
  hipMemsetAsync(gp0, 0, (size_t)N_GRAPHS * INDIM * 4, stream);
  hipMemsetAsync(gp, 0, (size_t)4 * N_GRAPHS * HID * 4, stream);

  // build CSR (dst-indexed)
  k_hist<<<(N_EDGES + 255) / 256, 256, 0, stream>>>(edst, deg);
  k_scan<<<1, 1024, 0, stream>>>(deg, rowptr, cursor);
  k_scatter<<<(N_EDGES + 255) / 256, 256, 0, stream>>>(esrc, edst, cursor, csr);

  dim3 gemmGrid((N_NODES + 63) / 64, 4);
  int bnBlocks = (N_NODES * HID + 255) / 256;
  int poolBlocks = (N_NODES + 127) / 128;

  // pool input representation (hidden_rep[0] = x)
  k_pool<INDIM><<<poolBlocks, INDIM, 0, stream>>>(x, gid, gp0);

  // ---- layer 0 (input dim 128) ----
  k_spmm<INDIM><<<N_NODES, INDIM, 0, stream>>>(x, rowptr, csr, bufA);
  k_gemm<INDIM><<<gemmGrid, 256, 0, stream>>>(bufA, mlp0_w1, mlp0_b1, bufB, N_NODES);
  k_colstats<<<256, 256, 0, stream>>>(bufB, stats, N_NODES);
  k_bn_relu<<<bnBlocks, 256, 0, stream>>>(bufB, stats, mlp0_bng, mlp0_bnb);
  k_gemm<HID><<<gemmGrid, 256, 0, stream>>>(bufB, mlp0_w2, mlp0_b2, bufA, N_NODES);
  k_colstats<<<256, 256, 0, stream>>>(bufA, stats + 512, N_NODES);
  k_bn_relu<<<bnBlocks, 256, 0, stream>>>(bufA, stats + 512, bng, bnb);
  k_pool<HID><<<poolBlocks, HID, 0, stream>>>(bufA, gid, gp);

  // ---- layers 1..3 ----
  float* h = bufA;
  float* other = bufB;
  for (int l = 1; l < 4; ++l) {
    int li = l - 1;
    k_spmm<HID><<<N_NODES, HID, 0, stream>>>(h, rowptr, csr, other);
    k_gemm<HID><<<gemmGrid, 256, 0, stream>>>(other, mlps_w1 + (size_t)li * HID * HID,
                                              mlps_b1 + li * HID, h, N_NODES);
    k_colstats<<<256, 256, 0, stream>>>(h, stats + (size_t)(2 * l) * 512, N_NODES);
    k_bn_relu<<<bnBlocks, 256, 0, stream>>>(h, stats + (size_t)(2 * l) * 512,
                                            mlps_bng + li * HID, mlps_bnb + li * HID);
    k_gemm<HID><<<gemmGrid, 256, 0, stream>>>(h, mlps_w2 + (size_t)li * HID * HID,
                                              mlps_b2 + li * HID, other, N_NODES);
    k_colstats<<<256, 256, 0, stream>>>(other, stats + (size_t)(2 * l + 1) * 512, N_NODES);
    k_bn_relu<<<bnBlocks, 256, 0, stream>>>(other, stats + (size_t)(2 * l + 1) * 512,
                                            bng + l * HID, bnb + l * HID);
    k_pool<HID><<<poolBlocks, HID, 0, stream>>>(other, gid, gp + (size_t)l * N_GRAPHS * HID);
    float* t = h; h = other; other = t;
  }

  k_score<<<N_GRAPHS, 256, 0, stream>>>(gp0, gp, pw0, pb0, pw, pb, (float*)d_out);
}

// Round 2
// 1454.715 us; speedup vs baseline: 1.6073x; 1.6073x over previous
//
#include <hip/hip_runtime.h>

#define N_NODES 50000
#define N_EDGES 800000
#define N_GRAPHS 64
#define INDIM 128
#define HID 256
#define OUTD 10

typedef __attribute__((ext_vector_type(8))) short bf16x8;
typedef __attribute__((ext_vector_type(4))) float f32x4;
typedef __attribute__((ext_vector_type(2))) unsigned short u16x2;
typedef __attribute__((ext_vector_type(4))) unsigned short u16x4;
typedef __attribute__((ext_vector_type(8))) unsigned short u16x8;

__device__ __forceinline__ float b2f(unsigned short u) {
  union { unsigned int i; float f; } c;
  c.i = ((unsigned int)u) << 16;
  return c.f;
}
__device__ __forceinline__ unsigned short f2b(float f) {
  union { float f; unsigned int i; } c;
  c.f = f;
  unsigned int x = c.i + 0x7FFFu + ((c.i >> 16) & 1u);  // RNE
  return (unsigned short)(x >> 16);
}

__device__ __forceinline__ void gload16(const void* g, void* l) {
  __builtin_amdgcn_global_load_lds(
      (const __attribute__((address_space(1))) unsigned int*)g,
      (__attribute__((address_space(3))) unsigned int*)l, 16, 0, 0);
}

// ---------------- CSR build ----------------
__global__ void k_hist(const int* __restrict__ dst, int* __restrict__ deg) {
  int e = blockIdx.x * blockDim.x + threadIdx.x;
  if (e < N_EDGES) atomicAdd(&deg[dst[e]], 1);
}

__global__ __launch_bounds__(1024) void k_scan(const int* __restrict__ deg,
                                               int* __restrict__ rowptr,
                                               int* __restrict__ cursor) {
  __shared__ int part[1024];
  const int n = N_NODES;
  const int per = (n + 1023) / 1024;
  int tid = threadIdx.x;
  int base = tid * per;
  int s = 0;
  for (int i = 0; i < per; ++i) {
    int idx = base + i;
    if (idx < n) s += deg[idx];
  }
  part[tid] = s;
  __syncthreads();
  for (int off = 1; off < 1024; off <<= 1) {
    int v = (tid >= off) ? part[tid - off] : 0;
    __syncthreads();
    part[tid] += v;
    __syncthreads();
  }
  int run = (tid == 0) ? 0 : part[tid - 1];
  for (int i = 0; i < per; ++i) {
    int idx = base + i;
    if (idx < n) {
      rowptr[idx] = run;
      cursor[idx] = run;
      run += deg[idx];
    }
  }
  if (tid == 0) rowptr[n] = part[1023];
}

__global__ void k_scatter(const int* __restrict__ src, const int* __restrict__ dst,
                          int* __restrict__ cursor, int* __restrict__ csr) {
  int e = blockIdx.x * blockDim.x + threadIdx.x;
  if (e < N_EDGES) {
    int pos = atomicAdd(&cursor[dst[e]], 1);
    csr[pos] = src[e];
  }
}

// ---------------- converts ----------------
__global__ void k_f2b4(const float* __restrict__ in, unsigned short* __restrict__ out,
                       size_t n4) {
  size_t i = ((size_t)blockIdx.x * blockDim.x + threadIdx.x);
  if (i >= n4) return;
  const float4 v = *(const float4*)&in[i * 4];
  u16x4 o = {f2b(v.x), f2b(v.y), f2b(v.z), f2b(v.w)};
  *(u16x4*)&out[i * 4] = o;
}

// W[K][256] f32 -> out[256][K] bf16 (transposed)
__global__ void k_wt(const float* __restrict__ W, unsigned short* __restrict__ out, int K) {
  int o = blockIdx.x * blockDim.x + threadIdx.x;
  if (o >= K * HID) return;
  int c = o / K, k = o - c * K;
  out[o] = f2b(W[(size_t)k * HID + c]);
}

// ---------------- SpMM bf16: out[n] = h[n] + sum_{dst=n} h[src] ----------------
template <int DIM>
__global__ __launch_bounds__(256) void k_spmm_b(const unsigned short* __restrict__ h,
                                                const int* __restrict__ rowptr,
                                                const int* __restrict__ csr,
                                                unsigned short* __restrict__ out) {
  constexpr int VEC = DIM / 64;
  int lane = threadIdx.x & 63;
  int node = blockIdx.x * 4 + (threadIdx.x >> 6);
  int cbase = lane * VEC;
  float acc[VEC];
  {
    const unsigned short* p = h + (size_t)node * DIM + cbase;
    if constexpr (VEC == 4) {
      u16x4 v = *(const u16x4*)p;
#pragma unroll
      for (int j = 0; j < 4; ++j) acc[j] = b2f(v[j]);
    } else {
      u16x2 v = *(const u16x2*)p;
#pragma unroll
      for (int j = 0; j < 2; ++j) acc[j] = b2f(v[j]);
    }
  }
  int b = rowptr[node], e = rowptr[node + 1];
  int i = b;
  for (; i + 1 < e; i += 2) {
    int s0 = csr[i], s1 = csr[i + 1];
    const unsigned short* p0 = h + (size_t)s0 * DIM + cbase;
    const unsigned short* p1 = h + (size_t)s1 * DIM + cbase;
    if constexpr (VEC == 4) {
      u16x4 v0 = *(const u16x4*)p0;
      u16x4 v1 = *(const u16x4*)p1;
#pragma unroll
      for (int j = 0; j < 4; ++j) acc[j] += b2f(v0[j]) + b2f(v1[j]);
    } else {
      u16x2 v0 = *(const u16x2*)p0;
      u16x2 v1 = *(const u16x2*)p1;
#pragma unroll
      for (int j = 0; j < 2; ++j) acc[j] += b2f(v0[j]) + b2f(v1[j]);
    }
  }
  if (i < e) {
    int s0 = csr[i];
    const unsigned short* p0 = h + (size_t)s0 * DIM + cbase;
    if constexpr (VEC == 4) {
      u16x4 v0 = *(const u16x4*)p0;
#pragma unroll
      for (int j = 0; j < 4; ++j) acc[j] += b2f(v0[j]);
    } else {
      u16x2 v0 = *(const u16x2*)p0;
#pragma unroll
      for (int j = 0; j < 2; ++j) acc[j] += b2f(v0[j]);
    }
  }
  if constexpr (VEC == 4) {
    u16x4 o = {f2b(acc[0]), f2b(acc[1]), f2b(acc[2]), f2b(acc[3])};
    *(u16x4*)&out[(size_t)node * DIM + cbase] = o;
  } else {
    u16x2 o = {f2b(acc[0]), f2b(acc[1])};
    *(u16x2*)&out[(size_t)node * DIM + cbase] = o;
  }
}

// ---------------- MFMA GEMM: C[M][256] = A[M][K] @ W[K][256] + bias (bf16 in/out) ----
// Wt is W pre-transposed: Wt[256][K]. Tiles: BM=128, BN=128, BK=64.
// LDS layout for both A and B(t): [128 rows][64 k] bf16, XOR-swizzled in 16B granules:
//   LDS[row][g] holds global granule (g ^ (row&7)); staged via per-lane pre-swizzled
//   global source addresses (linear LDS dest, guide §5/m173 pattern).
template <int K>
__global__ __launch_bounds__(256) void k_gemm_mfma(const unsigned short* __restrict__ A,
                                                   const unsigned short* __restrict__ Wt,
                                                   const float* __restrict__ bias,
                                                   unsigned short* __restrict__ C, int M) {
  __shared__ short As[128 * 64];
  __shared__ short Bs[128 * 64];
  const int tid = threadIdx.x;
  const int lane = tid & 63;
  const int wv = tid >> 6;
  const int wm = wv >> 1, wn = wv & 1;
  const int l16 = lane & 15, lh = lane >> 4;
  const int rB = blockIdx.x * 128;
  const int cB = blockIdx.y * 128;
  f32x4 acc[4][4] = {};

  for (int kt = 0; kt < K / 64; ++kt) {
#pragma unroll
    for (int it = 0; it < 8; ++it) {
      int s = it * 256 + tid;
      if (s < 1024) {
        int r = s >> 3, g = s & 7;
        int gs = g ^ (r & 7);
        int row = rB + r;
        if (row > M - 1) row = M - 1;
        gload16(A + (size_t)row * K + kt * 64 + gs * 8, &As[s * 8]);
      } else {
        int s2 = s - 1024;
        int r = s2 >> 3, g = s2 & 7;
        int gs = g ^ (r & 7);
        gload16(Wt + (size_t)(cB + r) * K + kt * 64 + gs * 8, &Bs[s2 * 8]);
      }
    }
    __syncthreads();
#pragma unroll
    for (int kh = 0; kh < 2; ++kh) {
      bf16x8 af[4], bfr[4];
      const int gsw = (kh * 4 + lh) ^ (l16 & 7);
#pragma unroll
      for (int m = 0; m < 4; ++m) {
        int row = wm * 64 + m * 16 + l16;
        af[m] = *(const bf16x8*)&As[row * 64 + gsw * 8];
      }
#pragma unroll
      for (int n = 0; n < 4; ++n) {
        int col = wn * 64 + n * 16 + l16;
        bfr[n] = *(const bf16x8*)&Bs[col * 64 + gsw * 8];
      }
#pragma unroll
      for (int m = 0; m < 4; ++m)
#pragma unroll
        for (int n = 0; n < 4; ++n)
          acc[m][n] =
              __builtin_amdgcn_mfma_f32_16x16x32_bf16(af[m], bfr[n], acc[m][n], 0, 0, 0);
    }
    __syncthreads();
  }

#pragma unroll
  for (int n = 0; n < 4; ++n) {
    int col = cB + wn * 64 + n * 16 + l16;
    float bv = bias[col];
#pragma unroll
    for (int m = 0; m < 4; ++m) {
#pragma unroll
      for (int r = 0; r < 4; ++r) {
        int row = rB + wm * 64 + m * 16 + lh * 4 + r;
        if (row < M) C[(size_t)row * HID + col] = f2b(acc[m][n][r] + bv);
      }
    }
  }
}

// ---------------- BN column stats (sum, sumsq) on bf16 ----------------
__global__ __launch_bounds__(256) void k_colstats_b(const unsigned short* __restrict__ X,
                                                    float* __restrict__ st, int M) {
  int c = threadIdx.x;
  float s = 0.f, s2 = 0.f;
  for (int r = blockIdx.x; r < M; r += gridDim.x) {
    float v = b2f(X[(size_t)r * HID + c]);
    s += v;
    s2 += v * v;
  }
  atomicAdd(&st[c], s);
  atomicAdd(&st[HID + c], s2);
}

// ---------------- BN apply + ReLU (in place, bf16) ----------------
__global__ __launch_bounds__(256) void k_bn_relu_b(unsigned short* __restrict__ X,
                                                   const float* __restrict__ st,
                                                   const float* __restrict__ g,
                                                   const float* __restrict__ b) {
  __shared__ float sc[HID], sh[HID];
  int tid = threadIdx.x;
  {
    const float invM = 1.0f / N_NODES;
    float mean = st[tid] * invM;
    float var = st[HID + tid] * invM - mean * mean;
    float s = g[tid] * rsqrtf(var + 1e-5f);
    sc[tid] = s;
    sh[tid] = b[tid] - mean * s;
  }
  __syncthreads();
  size_t i8 = ((size_t)blockIdx.x * 256 + tid) * 8;
  u16x8 v = *(const u16x8*)&X[i8];
  int c0 = (int)(i8 & (HID - 1));
  u16x8 o;
#pragma unroll
  for (int j = 0; j < 8; ++j) {
    float f = b2f(v[j]) * sc[c0 + j] + sh[c0 + j];
    o[j] = f2b(f > 0.f ? f : 0.f);
  }
  *(u16x8*)&X[i8] = o;
}

// ---------------- graph sum-pool (graph_id sorted) ----------------
__global__ void k_pool_f32(const float* __restrict__ H, const int* __restrict__ gid,
                           float* __restrict__ gp) {
  const int CHUNK = 128;
  int base = blockIdx.x * CHUNK;
  int c = threadIdx.x;  // INDIM threads
  int end = base + CHUNK;
  if (end > N_NODES) end = N_NODES;
  int cur = gid[base];
  float acc = 0.f;
  for (int r = base; r < end; ++r) {
    int g = gid[r];
    if (g != cur) {
      atomicAdd(&gp[(size_t)cur * INDIM + c], acc);
      acc = 0.f;
      cur = g;
    }
    acc += H[(size_t)r * INDIM + c];
  }
  atomicAdd(&gp[(size_t)cur * INDIM + c], acc);
}

__global__ void k_pool_b(const unsigned short* __restrict__ H, const int* __restrict__ gid,
                         float* __restrict__ gp) {
  const int CHUNK = 128;
  int base = blockIdx.x * CHUNK;
  int c = threadIdx.x;  // 256 threads
  int end = base + CHUNK;
  if (end > N_NODES) end = N_NODES;
  int cur = gid[base];
  float acc = 0.f;
  for (int r = base; r < end; ++r) {
    int g = gid[r];
    if (g != cur) {
      atomicAdd(&gp[(size_t)cur * HID + c], acc);
      acc = 0.f;
      cur = g;
    }
    acc += b2f(H[(size_t)r * HID + c]);
  }
  atomicAdd(&gp[(size_t)cur * HID + c], acc);
}

// ---------------- final prediction heads ----------------
__global__ __launch_bounds__(256) void k_score(const float* __restrict__ gp0,
                                               const float* __restrict__ gp,
                                               const float* __restrict__ pw0,
                                               const float* __restrict__ pb0,
                                               const float* __restrict__ pw,
                                               const float* __restrict__ pb,
                                               float* __restrict__ out) {
  __shared__ float red[256];
  int g = blockIdx.x;
  int tid = threadIdx.x;
  for (int o = 0; o < OUTD; ++o) {
    float p = 0.f;
    if (tid < INDIM) p += gp0[g * INDIM + tid] * pw0[tid * OUTD + o];
#pragma unroll
    for (int l = 0; l < 4; ++l)
      p += gp[((size_t)l * N_GRAPHS + g) * HID + tid] * pw[(size_t)(l * HID + tid) * OUTD + o];
    red[tid] = p;
    __syncthreads();
    for (int s = 128; s > 0; s >>= 1) {
      if (tid < s) red[tid] += red[tid + s];
      __syncthreads();
    }
    if (tid == 0) {
      float r = red[0] + pb0[o];
      for (int l = 0; l < 4; ++l) r += pb[l * OUTD + o];
      out[g * OUTD + o] = r;
    }
    __syncthreads();
  }
}

extern "C" void kernel_launch(void* const* d_in, const int* in_sizes, int n_in,
                              void* d_out, int out_size, void* d_ws, size_t ws_size,
                              hipStream_t stream) {
  (void)in_sizes; (void)n_in; (void)out_size; (void)ws_size;
  const float* x = (const float*)d_in[0];
  const float* mlp0_w1 = (const float*)d_in[1];
  const float* mlp0_b1 = (const float*)d_in[2];
  const float* mlp0_bng = (const float*)d_in[3];
  const float* mlp0_bnb = (const float*)d_in[4];
  const float* mlp0_w2 = (const float*)d_in[5];
  const float* mlp0_b2 = (const float*)d_in[6];
  const float* mlps_w1 = (const float*)d_in[7];
  const float* mlps_b1 = (const float*)d_in[8];
  const float* mlps_bng = (const float*)d_in[9];
  const float* mlps_bnb = (const float*)d_in[10];
  const float* mlps_w2 = (const float*)d_in[11];
  const float* mlps_b2 = (const float*)d_in[12];
  const float* bng = (const float*)d_in[13];
  const float* bnb = (const float*)d_in[14];
  const float* pw0 = (const float*)d_in[15];
  const float* pb0 = (const float*)d_in[16];
  const float* pw = (const float*)d_in[17];
  const float* pb = (const float*)d_in[18];
  const int* eidx = (const int*)d_in[19];
  const int* gid = (const int*)d_in[20];
  const int* esrc = eidx;
  const int* edst = eidx + N_EDGES;

  char* w = (char*)d_ws;
  size_t off = 0;
  auto take = [&](size_t bytes) -> void* {
    void* p = w + off;
    off += (bytes + 255) & ~(size_t)255;
    return p;
  };
  unsigned short* xb = (unsigned short*)take((size_t)N_NODES * INDIM * 2);
  unsigned short* bufA = (unsigned short*)take((size_t)N_NODES * HID * 2);
  unsigned short* bufB = (unsigned short*)take((size_t)N_NODES * HID * 2);
  unsigned short* wt0_1 = (unsigned short*)take((size_t)HID * INDIM * 2);
  unsigned short* wt0_2 = (unsigned short*)take((size_t)HID * HID * 2);
  unsigned short* wts_1 = (unsigned short*)take((size_t)3 * HID * HID * 2);
  unsigned short* wts_2 = (unsigned short*)take((size_t)3 * HID * HID * 2);
  int* deg = (int*)take((size_t)N_NODES * 4);
  int* rowptr = (int*)take((size_t)(N_NODES + 1) * 4);
  int* cursor = (int*)take((size_t)N_NODES * 4);
  int* csr = (int*)take((size_t)N_EDGES * 4);
  float* stats = (float*)take(8 * 512 * 4);
  float* gp0 = (float*)take((size_t)N_GRAPHS * INDIM * 4);
  float* gp = (float*)take((size_t)4 * N_GRAPHS * HID * 4);

  hipMemsetAsync(deg, 0, (size_t)N_NODES * 4, stream);
  hipMemsetAsync(stats, 0, 8 * 512 * 4, stream);
  hipMemsetAsync(gp0, 0, (size_t)N_GRAPHS * INDIM * 4, stream);
  hipMemsetAsync(gp, 0, (size_t)4 * N_GRAPHS * HID * 4, stream);

  // prep: converts + weight transposes + CSR
  k_f2b4<<<(N_NODES * INDIM / 4 + 255) / 256, 256, 0, stream>>>(x, xb,
                                                                (size_t)N_NODES * INDIM / 4);
  k_wt<<<(INDIM * HID + 255) / 256, 256, 0, stream>>>(mlp0_w1, wt0_1, INDIM);
  k_wt<<<(HID * HID + 255) / 256, 256, 0, stream>>>(mlp0_w2, wt0_2, HID);
  for (int i = 0; i < 3; ++i) {
    k_wt<<<(HID * HID + 255) / 256, 256, 0, stream>>>(mlps_w1 + (size_t)i * HID * HID,
                                                      wts_1 + (size_t)i * HID * HID, HID);
    k_wt<<<(HID * HID + 255) / 256, 256, 0, stream>>>(mlps_w2 + (size_t)i * HID * HID,
                                                      wts_2 + (size_t)i * HID * HID, HID);
  }
  k_hist<<<(N_EDGES + 255) / 256, 256, 0, stream>>>(edst, deg);
  k_scan<<<1, 1024, 0, stream>>>(deg, rowptr, cursor);
  k_scatter<<<(N_EDGES + 255) / 256, 256, 0, stream>>>(esrc, edst, cursor, csr);

  dim3 gemmGrid((N_NODES + 127) / 128, 2);
  const int bnGrid = N_NODES * HID / (256 * 8);  // 6250, exact
  const int poolGrid = (N_NODES + 127) / 128;
  const int spmmGrid = (N_NODES + 3) / 4;

  // pool input representation (hidden_rep[0] = x, f32)
  k_pool_f32<<<poolGrid, INDIM, 0, stream>>>(x, gid, gp0);

  // ---- layer 0 (input dim 128) ----
  k_spmm_b<INDIM><<<spmmGrid, 256, 0, stream>>>(xb, rowptr, csr, bufA);
  k_gemm_mfma<INDIM><<<gemmGrid, 256, 0, stream>>>(bufA, wt0_1, mlp0_b1, bufB, N_NODES);
  k_colstats_b<<<256, 256, 0, stream>>>(bufB, stats, N_NODES);
  k_bn_relu_b<<<bnGrid, 256, 0, stream>>>(bufB, stats, mlp0_bng, mlp0_bnb);
  k_gemm_mfma<HID><<<gemmGrid, 256, 0, stream>>>(bufB, wt0_2, mlp0_b2, bufA, N_NODES);
  k_colstats_b<<<256, 256, 0, stream>>>(bufA, stats + 512, N_NODES);
  k_bn_relu_b<<<bnGrid, 256, 0, stream>>>(bufA, stats + 512, bng, bnb);
  k_pool_b<<<poolGrid, 256, 0, stream>>>(bufA, gid, gp);

  // ---- layers 1..3 ----
  unsigned short* h = bufA;
  unsigned short* other = bufB;
  for (int l = 1; l < 4; ++l) {
    int li = l - 1;
    k_spmm_b<HID><<<spmmGrid, 256, 0, stream>>>(h, rowptr, csr, other);
    k_gemm_mfma<HID><<<gemmGrid, 256, 0, stream>>>(other, wts_1 + (size_t)li * HID * HID,
                                                   mlps_b1 + li * HID, h, N_NODES);
    k_colstats_b<<<256, 256, 0, stream>>>(h, stats + (size_t)(2 * l) * 512, N_NODES);
    k_bn_relu_b<<<bnGrid, 256, 0, stream>>>(h, stats + (size_t)(2 * l) * 512,
                                            mlps_bng + li * HID, mlps_bnb + li * HID);
    k_gemm_mfma<HID><<<gemmGrid, 256, 0, stream>>>(h, wts_2 + (size_t)li * HID * HID,
                                                   mlps_b2 + li * HID, other, N_NODES);
    k_colstats_b<<<256, 256, 0, stream>>>(other, stats + (size_t)(2 * l + 1) * 512, N_NODES);
    k_bn_relu_b<<<bnGrid, 256, 0, stream>>>(other, stats + (size_t)(2 * l + 1) * 512,
                                            bng + l * HID, bnb + l * HID);
    k_pool_b<<<poolGrid, 256, 0, stream>>>(other, gid, gp + (size_t)l * N_GRAPHS * HID);
    unsigned short* t = h;
    h = other;
    other = t;
  }

  k_score<<<N_GRAPHS, 256, 0, stream>>>(gp0, gp, pw0, pb0, pw, pb, (float*)d_out);
}

// Round 3
// 856.232 us; speedup vs baseline: 2.7307x; 1.6990x over previous
//
#include <hip/hip_runtime.h>

#define N_NODES 50000
#define N_EDGES 800000
#define N_GRAPHS 64
#define INDIM 128
#define HID 256
#define OUTD 10

typedef __attribute__((ext_vector_type(8))) short bf16x8;
typedef __attribute__((ext_vector_type(4))) float f32x4;
typedef __attribute__((ext_vector_type(4))) unsigned short u16x4;
typedef __attribute__((ext_vector_type(8))) unsigned short u16x8;

__device__ __forceinline__ float b2f(unsigned short u) {
  union { unsigned int i; float f; } c;
  c.i = ((unsigned int)u) << 16;
  return c.f;
}
__device__ __forceinline__ unsigned short f2b(float f) {
  union { float f; unsigned int i; } c;
  c.f = f;
  unsigned int x = c.i + 0x7FFFu + ((c.i >> 16) & 1u);  // RNE
  return (unsigned short)(x >> 16);
}

__device__ __forceinline__ void gload16(const void* g, void* l) {
  __builtin_amdgcn_global_load_lds(
      (const __attribute__((address_space(1))) unsigned int*)g,
      (__attribute__((address_space(3))) unsigned int*)l, 16, 0, 0);
}

// ---------------- CSR build ----------------
__global__ void k_hist(const int* __restrict__ dst, int* __restrict__ deg) {
  int e = blockIdx.x * blockDim.x + threadIdx.x;
  if (e < N_EDGES) atomicAdd(&deg[dst[e]], 1);
}

#define SCAN_NB ((N_NODES + 255) / 256)  // 196

__global__ __launch_bounds__(256) void k_scan1(const int* __restrict__ deg,
                                               int* __restrict__ bsum) {
  int i = blockIdx.x * 256 + threadIdx.x;
  int v = (i < N_NODES) ? deg[i] : 0;
#pragma unroll
  for (int m = 1; m < 64; m <<= 1) v += __shfl_xor(v, m, 64);
  __shared__ int ws[4];
  if ((threadIdx.x & 63) == 0) ws[threadIdx.x >> 6] = v;
  __syncthreads();
  if (threadIdx.x == 0) bsum[blockIdx.x] = ws[0] + ws[1] + ws[2] + ws[3];
}

__global__ __launch_bounds__(256) void k_scan2(const int* __restrict__ bsum,
                                               int* __restrict__ boff) {
  __shared__ int s[256];
  int t = threadIdx.x;
  s[t] = (t < SCAN_NB) ? bsum[t] : 0;
  __syncthreads();
  for (int o = 1; o < 256; o <<= 1) {
    int v = (t >= o) ? s[t - o] : 0;
    __syncthreads();
    s[t] += v;
    __syncthreads();
  }
  if (t < SCAN_NB) boff[t] = (t == 0) ? 0 : s[t - 1];
}

__global__ __launch_bounds__(256) void k_scan3(const int* __restrict__ deg,
                                               const int* __restrict__ boff,
                                               int* __restrict__ rowptr,
                                               int* __restrict__ cursor) {
  __shared__ int s[256];
  int t = threadIdx.x;
  int i = blockIdx.x * 256 + t;
  int v = (i < N_NODES) ? deg[i] : 0;
  s[t] = v;
  __syncthreads();
  for (int o = 1; o < 256; o <<= 1) {
    int w = (t >= o) ? s[t - o] : 0;
    __syncthreads();
    s[t] += w;
    __syncthreads();
  }
  int excl = ((t == 0) ? 0 : s[t - 1]) + boff[blockIdx.x];
  if (i < N_NODES) {
    rowptr[i] = excl;
    cursor[i] = excl;
    if (i == N_NODES - 1) rowptr[N_NODES] = excl + v;
  }
}

__global__ void k_scatter(const int* __restrict__ src, const int* __restrict__ dst,
                          int* __restrict__ cursor, int* __restrict__ csr) {
  int e = blockIdx.x * blockDim.x + threadIdx.x;
  if (e < N_EDGES) {
    int pos = atomicAdd(&cursor[dst[e]], 1);
    csr[pos] = src[e];
  }
}

// ---------------- converts ----------------
__global__ void k_f2b4(const float* __restrict__ in, unsigned short* __restrict__ out,
                       size_t n4) {
  size_t i = ((size_t)blockIdx.x * blockDim.x + threadIdx.x);
  if (i >= n4) return;
  const float4 v = *(const float4*)&in[i * 4];
  u16x4 o = {f2b(v.x), f2b(v.y), f2b(v.z), f2b(v.w)};
  *(u16x4*)&out[i * 4] = o;
}

// W[K][256] f32 -> out[256][K] bf16 (transposed)
__global__ void k_wt(const float* __restrict__ W, unsigned short* __restrict__ out, int K) {
  int o = blockIdx.x * blockDim.x + threadIdx.x;
  if (o >= K * HID) return;
  int c = o / K, k = o - c * K;
  out[o] = f2b(W[(size_t)k * HID + c]);
}

// ---------------- SpMM: out[n] = f(h[n]) + sum_{dst=n} f(h[src]) ----------------
// f = identity (BN=false) or relu(bn(.)) with given stats (BN=true).
// One wave per node; NG row-streams of RL lanes x 16B; shfl-combine at end.
template <int DIM, bool BN>
__global__ __launch_bounds__(256) void k_spmm2(const unsigned short* __restrict__ h,
                                               const int* __restrict__ rowptr,
                                               const int* __restrict__ csr,
                                               const float* __restrict__ st,
                                               const float* __restrict__ g,
                                               const float* __restrict__ bb,
                                               unsigned short* __restrict__ out) {
  constexpr int RL = DIM / 8;  // lanes per row (16B each)
  constexpr int NG = 64 / RL;  // concurrent row streams per wave
  const int lane = threadIdx.x & 63;
  const int node = blockIdx.x * 4 + (threadIdx.x >> 6);
  const int grp = lane / RL;
  const int cbase = (lane % RL) * 8;
  float sc[8], sh[8];
  if constexpr (BN) {
    const float invM = 1.0f / N_NODES;
#pragma unroll
    for (int q = 0; q < 8; ++q) {
      int c = cbase + q;
      float mean = st[c] * invM;
      float var = st[HID + c] * invM - mean * mean;
      float s = g[c] * rsqrtf(var + 1e-5f);
      sc[q] = s;
      sh[q] = bb[c] - mean * s;
    }
  }
  const int b = rowptr[node], e = rowptr[node + 1];
  const int count = e - b + 1;  // virtual list: [self] + neighbors
  float acc[8] = {};
  int j = grp;
  for (; j + NG < count; j += 2 * NG) {
    int r0 = (j == 0) ? node : csr[b + j - 1];
    int r1 = csr[b + j + NG - 1];
    u16x8 v0 = *(const u16x8*)(h + (size_t)r0 * DIM + cbase);
    u16x8 v1 = *(const u16x8*)(h + (size_t)r1 * DIM + cbase);
#pragma unroll
    for (int q = 0; q < 8; ++q) {
      float f0 = b2f(v0[q]), f1 = b2f(v1[q]);
      if constexpr (BN) {
        f0 = f0 * sc[q] + sh[q];
        f0 = f0 > 0.f ? f0 : 0.f;
        f1 = f1 * sc[q] + sh[q];
        f1 = f1 > 0.f ? f1 : 0.f;
      }
      acc[q] += f0 + f1;
    }
  }
  if (j < count) {
    int r0 = (j == 0) ? node : csr[b + j - 1];
    u16x8 v0 = *(const u16x8*)(h + (size_t)r0 * DIM + cbase);
#pragma unroll
    for (int q = 0; q < 8; ++q) {
      float f0 = b2f(v0[q]);
      if constexpr (BN) {
        f0 = f0 * sc[q] + sh[q];
        f0 = f0 > 0.f ? f0 : 0.f;
      }
      acc[q] += f0;
    }
  }
#pragma unroll
  for (int m = RL; m < 64; m <<= 1)
#pragma unroll
    for (int q = 0; q < 8; ++q) acc[q] += __shfl_xor(acc[q], m, 64);
  if (grp == 0) {
    u16x8 o;
#pragma unroll
    for (int q = 0; q < 8; ++q) o[q] = f2b(acc[q]);
    *(u16x8*)(out + (size_t)node * DIM + cbase) = o;
  }
}

// ---------------- MFMA GEMM + fused column stats ----------------
// C[M][256] = A[M][K] @ Wt^T + bias (bf16 in/out); stats stage gets col sum/sumsq.
template <int K>
__global__ __launch_bounds__(256) void k_gemm_mfma(const unsigned short* __restrict__ A,
                                                   const unsigned short* __restrict__ Wt,
                                                   const float* __restrict__ bias,
                                                   float* __restrict__ stout,
                                                   unsigned short* __restrict__ C, int M) {
  __shared__ short As[128 * 64];
  __shared__ short Bs[128 * 64];
  __shared__ float s_sum[128], s_sqs[128];
  const int tid = threadIdx.x;
  const int lane = tid & 63;
  const int wv = tid >> 6;
  const int wm = wv >> 1, wn = wv & 1;
  const int l16 = lane & 15, lh = lane >> 4;
  const int rB = blockIdx.x * 128;
  const int cB = blockIdx.y * 128;
  f32x4 acc[4][4] = {};
  if (tid < 128) {
    s_sum[tid] = 0.f;
    s_sqs[tid] = 0.f;
  }

  for (int kt = 0; kt < K / 64; ++kt) {
#pragma unroll
    for (int it = 0; it < 8; ++it) {
      int s = it * 256 + tid;
      if (s < 1024) {
        int r = s >> 3, g = s & 7;
        int gs = g ^ (r & 7);
        int row = rB + r;
        if (row > M - 1) row = M - 1;
        gload16(A + (size_t)row * K + kt * 64 + gs * 8, &As[s * 8]);
      } else {
        int s2 = s - 1024;
        int r = s2 >> 3, g = s2 & 7;
        int gs = g ^ (r & 7);
        gload16(Wt + (size_t)(cB + r) * K + kt * 64 + gs * 8, &Bs[s2 * 8]);
      }
    }
    __syncthreads();
#pragma unroll
    for (int kh = 0; kh < 2; ++kh) {
      bf16x8 af[4], bfr[4];
      const int gsw = (kh * 4 + lh) ^ (l16 & 7);
#pragma unroll
      for (int m = 0; m < 4; ++m) {
        int row = wm * 64 + m * 16 + l16;
        af[m] = *(const bf16x8*)&As[row * 64 + gsw * 8];
      }
#pragma unroll
      for (int n = 0; n < 4; ++n) {
        int col = wn * 64 + n * 16 + l16;
        bfr[n] = *(const bf16x8*)&Bs[col * 64 + gsw * 8];
      }
#pragma unroll
      for (int m = 0; m < 4; ++m)
#pragma unroll
        for (int n = 0; n < 4; ++n)
          acc[m][n] =
              __builtin_amdgcn_mfma_f32_16x16x32_bf16(af[m], bfr[n], acc[m][n], 0, 0, 0);
    }
    __syncthreads();
  }

#pragma unroll
  for (int n = 0; n < 4; ++n) {
    int colL = wn * 64 + n * 16 + l16;
    int col = cB + colL;
    float bv = bias[col];
    float ps = 0.f, pq = 0.f;
#pragma unroll
    for (int m = 0; m < 4; ++m) {
#pragma unroll
      for (int r = 0; r < 4; ++r) {
        int row = rB + wm * 64 + m * 16 + lh * 4 + r;
        if (row < M) {
          float val = acc[m][n][r] + bv;
          ps += val;
          pq += val * val;
          C[(size_t)row * HID + col] = f2b(val);
        }
      }
    }
    atomicAdd(&s_sum[colL], ps);
    atomicAdd(&s_sqs[colL], pq);
  }
  __syncthreads();
  if (tid < 128) {
    atomicAdd(&stout[cB + tid], s_sum[tid]);
    atomicAdd(&stout[HID + cB + tid], s_sqs[tid]);
  }
}

// ---------------- inner BN apply + ReLU (in place, bf16) ----------------
__global__ __launch_bounds__(256) void k_bn_relu_b(unsigned short* __restrict__ X,
                                                   const float* __restrict__ st,
                                                   const float* __restrict__ g,
                                                   const float* __restrict__ b) {
  __shared__ float sc[HID], sh[HID];
  int tid = threadIdx.x;
  {
    const float invM = 1.0f / N_NODES;
    float mean = st[tid] * invM;
    float var = st[HID + tid] * invM - mean * mean;
    float s = g[tid] * rsqrtf(var + 1e-5f);
    sc[tid] = s;
    sh[tid] = b[tid] - mean * s;
  }
  __syncthreads();
  size_t i8 = ((size_t)blockIdx.x * 256 + tid) * 8;
  u16x8 v = *(const u16x8*)&X[i8];
  int c0 = (int)(i8 & (HID - 1));
  u16x8 o;
#pragma unroll
  for (int j = 0; j < 8; ++j) {
    float f = b2f(v[j]) * sc[c0 + j] + sh[c0 + j];
    o[j] = f2b(f > 0.f ? f : 0.f);
  }
  *(u16x8*)&X[i8] = o;
}

// ---------------- graph sum-pool over relu(bn(raw)) (gid sorted) ----------------
__global__ __launch_bounds__(256) void k_pool_b2(const unsigned short* __restrict__ H,
                                                 const int* __restrict__ gid,
                                                 const float* __restrict__ st,
                                                 const float* __restrict__ g,
                                                 const float* __restrict__ bb,
                                                 float* __restrict__ gp) {
  const int lane = threadIdx.x & 63;
  const int wv = threadIdx.x >> 6;
  const int grp = lane >> 5;
  const int cbase = (lane & 31) * 8;
  float sc[8], sh[8];
  {
    const float invM = 1.0f / N_NODES;
#pragma unroll
    for (int q = 0; q < 8; ++q) {
      int c = cbase + q;
      float mean = st[c] * invM;
      float var = st[HID + c] * invM - mean * mean;
      float s = g[c] * rsqrtf(var + 1e-5f);
      sc[q] = s;
      sh[q] = bb[c] - mean * s;
    }
  }
  int base = blockIdx.x * 256 + wv * 64 + grp;
  int end = blockIdx.x * 256 + wv * 64 + 64;
  if (end > N_NODES) end = N_NODES;
  float acc[8] = {};
  int cur = -1;
  for (int r = base; r < end; r += 2) {
    int gg = gid[r];
    if (gg != cur) {
      if (cur >= 0) {
#pragma unroll
        for (int q = 0; q < 8; ++q) {
          atomicAdd(&gp[(size_t)cur * HID + cbase + q], acc[q]);
          acc[q] = 0.f;
        }
      }
      cur = gg;
    }
    u16x8 v = *(const u16x8*)(H + (size_t)r * HID + cbase);
#pragma unroll
    for (int q = 0; q < 8; ++q) {
      float f = b2f(v[q]) * sc[q] + sh[q];
      acc[q] += f > 0.f ? f : 0.f;
    }
  }
  if (cur >= 0) {
#pragma unroll
    for (int q = 0; q < 8; ++q) atomicAdd(&gp[(size_t)cur * HID + cbase + q], acc[q]);
  }
}

// pool of raw f32 x [N][128]
__global__ __launch_bounds__(256) void k_pool_x(const float* __restrict__ X,
                                                const int* __restrict__ gid,
                                                float* __restrict__ gp) {
  const int lane = threadIdx.x & 63;
  const int wv = threadIdx.x >> 6;
  const int grp = lane >> 5;
  const int cbase = (lane & 31) * 4;
  int base = blockIdx.x * 256 + wv * 64 + grp;
  int end = blockIdx.x * 256 + wv * 64 + 64;
  if (end > N_NODES) end = N_NODES;
  float acc[4] = {};
  int cur = -1;
  for (int r = base; r < end; r += 2) {
    int gg = gid[r];
    if (gg != cur) {
      if (cur >= 0) {
#pragma unroll
        for (int q = 0; q < 4; ++q) {
          atomicAdd(&gp[(size_t)cur * INDIM + cbase + q], acc[q]);
          acc[q] = 0.f;
        }
      }
      cur = gg;
    }
    float4 v = *(const float4*)(X + (size_t)r * INDIM + cbase);
    acc[0] += v.x;
    acc[1] += v.y;
    acc[2] += v.z;
    acc[3] += v.w;
  }
  if (cur >= 0) {
#pragma unroll
    for (int q = 0; q < 4; ++q) atomicAdd(&gp[(size_t)cur * INDIM + cbase + q], acc[q]);
  }
}

// ---------------- final prediction heads ----------------
__global__ __launch_bounds__(256) void k_score(const float* __restrict__ gp0,
                                               const float* __restrict__ gp,
                                               const float* __restrict__ pw0,
                                               const float* __restrict__ pb0,
                                               const float* __restrict__ pw,
                                               const float* __restrict__ pb,
                                               float* __restrict__ out) {
  __shared__ float red[256];
  int g = blockIdx.x;
  int tid = threadIdx.x;
  for (int o = 0; o < OUTD; ++o) {
    float p = 0.f;
    if (tid < INDIM) p += gp0[g * INDIM + tid] * pw0[tid * OUTD + o];
#pragma unroll
    for (int l = 0; l < 4; ++l)
      p += gp[((size_t)l * N_GRAPHS + g) * HID + tid] * pw[(size_t)(l * HID + tid) * OUTD + o];
    red[tid] = p;
    __syncthreads();
    for (int s = 128; s > 0; s >>= 1) {
      if (tid < s) red[tid] += red[tid + s];
      __syncthreads();
    }
    if (tid == 0) {
      float r = red[0] + pb0[o];
      for (int l = 0; l < 4; ++l) r += pb[l * OUTD + o];
      out[g * OUTD + o] = r;
    }
    __syncthreads();
  }
}

extern "C" void kernel_launch(void* const* d_in, const int* in_sizes, int n_in,
                              void* d_out, int out_size, void* d_ws, size_t ws_size,
                              hipStream_t stream) {
  (void)in_sizes; (void)n_in; (void)out_size; (void)ws_size;
  const float* x = (const float*)d_in[0];
  const float* mlp0_w1 = (const float*)d_in[1];
  const float* mlp0_b1 = (const float*)d_in[2];
  const float* mlp0_bng = (const float*)d_in[3];
  const float* mlp0_bnb = (const float*)d_in[4];
  const float* mlp0_w2 = (const float*)d_in[5];
  const float* mlp0_b2 = (const float*)d_in[6];
  const float* mlps_w1 = (const float*)d_in[7];
  const float* mlps_b1 = (const float*)d_in[8];
  const float* mlps_bng = (const float*)d_in[9];
  const float* mlps_bnb = (const float*)d_in[10];
  const float* mlps_w2 = (const float*)d_in[11];
  const float* mlps_b2 = (const float*)d_in[12];
  const float* bng = (const float*)d_in[13];
  const float* bnb = (const float*)d_in[14];
  const float* pw0 = (const float*)d_in[15];
  const float* pb0 = (const float*)d_in[16];
  const float* pw = (const float*)d_in[17];
  const float* pb = (const float*)d_in[18];
  const int* eidx = (const int*)d_in[19];
  const int* gid = (const int*)d_in[20];
  const int* esrc = eidx;
  const int* edst = eidx + N_EDGES;

  char* w = (char*)d_ws;
  size_t off = 0;
  auto take = [&](size_t bytes) -> void* {
    void* p = w + off;
    off += (bytes + 255) & ~(size_t)255;
    return p;
  };
  unsigned short* xb = (unsigned short*)take((size_t)N_NODES * INDIM * 2);
  unsigned short* B0 = (unsigned short*)take((size_t)N_NODES * HID * 2);  // t2raw slot
  unsigned short* B1 = (unsigned short*)take((size_t)N_NODES * HID * 2);  // agg slot
  unsigned short* B2 = (unsigned short*)take((size_t)N_NODES * HID * 2);  // t1 slot
  unsigned short* wt0_1 = (unsigned short*)take((size_t)HID * INDIM * 2);
  unsigned short* wt0_2 = (unsigned short*)take((size_t)HID * HID * 2);
  unsigned short* wts_1 = (unsigned short*)take((size_t)3 * HID * HID * 2);
  unsigned short* wts_2 = (unsigned short*)take((size_t)3 * HID * HID * 2);
  int* deg = (int*)take((size_t)N_NODES * 4);
  int* rowptr = (int*)take((size_t)(N_NODES + 1) * 4);
  int* cursor = (int*)take((size_t)N_NODES * 4);
  int* csr = (int*)take((size_t)N_EDGES * 4);
  int* bsum = (int*)take((size_t)SCAN_NB * 4);
  int* boff = (int*)take((size_t)(SCAN_NB + 1) * 4);
  float* stats = (float*)take(8 * 512 * 4);
  float* gp0 = (float*)take((size_t)N_GRAPHS * INDIM * 4);
  float* gp = (float*)take((size_t)4 * N_GRAPHS * HID * 4);

  hipMemsetAsync(deg, 0, (size_t)N_NODES * 4, stream);
  hipMemsetAsync(stats, 0, 8 * 512 * 4, stream);
  hipMemsetAsync(gp0, 0, (size_t)N_GRAPHS * INDIM * 4, stream);
  hipMemsetAsync(gp, 0, (size_t)4 * N_GRAPHS * HID * 4, stream);

  // prep: converts + weight transposes + CSR
  k_f2b4<<<(N_NODES * INDIM / 4 + 255) / 256, 256, 0, stream>>>(x, xb,
                                                                (size_t)N_NODES * INDIM / 4);
  k_wt<<<(INDIM * HID + 255) / 256, 256, 0, stream>>>(mlp0_w1, wt0_1, INDIM);
  k_wt<<<(HID * HID + 255) / 256, 256, 0, stream>>>(mlp0_w2, wt0_2, HID);
  for (int i = 0; i < 3; ++i) {
    k_wt<<<(HID * HID + 255) / 256, 256, 0, stream>>>(mlps_w1 + (size_t)i * HID * HID,
                                                      wts_1 + (size_t)i * HID * HID, HID);
    k_wt<<<(HID * HID + 255) / 256, 256, 0, stream>>>(mlps_w2 + (size_t)i * HID * HID,
                                                      wts_2 + (size_t)i * HID * HID, HID);
  }
  k_hist<<<(N_EDGES + 255) / 256, 256, 0, stream>>>(edst, deg);
  k_scan1<<<SCAN_NB, 256, 0, stream>>>(deg, bsum);
  k_scan2<<<1, 256, 0, stream>>>(bsum, boff);
  k_scan3<<<SCAN_NB, 256, 0, stream>>>(deg, boff, rowptr, cursor);
  k_scatter<<<(N_EDGES + 255) / 256, 256, 0, stream>>>(esrc, edst, cursor, csr);

  dim3 gemmGrid((N_NODES + 127) / 128, 2);
  const int bnGrid = N_NODES * HID / (256 * 8);  // 6250, exact
  const int poolGrid = (N_NODES + 255) / 256;
  const int spmmGrid = (N_NODES + 3) / 4;

  // pool input representation (hidden_rep[0] = x, f32)
  k_pool_x<<<poolGrid, 256, 0, stream>>>(x, gid, gp0);

  // ---- layer 0 (input dim 128) ----
  k_spmm2<INDIM, false><<<spmmGrid, 256, 0, stream>>>(xb, rowptr, csr, nullptr, nullptr,
                                                      nullptr, B1);
  k_gemm_mfma<INDIM><<<gemmGrid, 256, 0, stream>>>(B1, wt0_1, mlp0_b1, stats, B2, N_NODES);
  k_bn_relu_b<<<bnGrid, 256, 0, stream>>>(B2, stats, mlp0_bng, mlp0_bnb);
  k_gemm_mfma<HID><<<gemmGrid, 256, 0, stream>>>(B2, wt0_2, mlp0_b2, stats + 512, B0,
                                                 N_NODES);
  k_pool_b2<<<poolGrid, 256, 0, stream>>>(B0, gid, stats + 512, bng, bnb, gp);

  // ---- layers 1..3 ----
  for (int l = 1; l < 4; ++l) {
    int li = l - 1;
    const float* stPrev = stats + (size_t)(2 * li + 1) * 512;
    const float* stIn = stats + (size_t)(2 * l) * 512;
    float* stInW = stats + (size_t)(2 * l) * 512;
    float* stOutW = stats + (size_t)(2 * l + 1) * 512;
    k_spmm2<HID, true><<<spmmGrid, 256, 0, stream>>>(B0, rowptr, csr, stPrev,
                                                     bng + li * HID, bnb + li * HID, B1);
    k_gemm_mfma<HID><<<gemmGrid, 256, 0, stream>>>(B1, wts_1 + (size_t)li * HID * HID,
                                                   mlps_b1 + li * HID, stInW, B2, N_NODES);
    k_bn_relu_b<<<bnGrid, 256, 0, stream>>>(B2, stIn, mlps_bng + li * HID,
                                            mlps_bnb + li * HID);
    k_gemm_mfma<HID><<<gemmGrid, 256, 0, stream>>>(B2, wts_2 + (size_t)li * HID * HID,
                                                   mlps_b2 + li * HID, stOutW, B0, N_NODES);
    k_pool_b2<<<poolGrid, 256, 0, stream>>>(B0, gid, stOutW, bng + l * HID, bnb + l * HID,
                                            gp + (size_t)l * N_GRAPHS * HID);
  }

  k_score<<<N_GRAPHS, 256, 0, stream>>>(gp0, gp, pw0, pb0, pw, pb, (float*)d_out);
}

// Round 4
// 853.869 us; speedup vs baseline: 2.7383x; 1.0028x over previous
//
#include <hip/hip_runtime.h>

#define N_NODES 50000
#define N_EDGES 800000
#define N_GRAPHS 64
#define INDIM 128
#define HID 256
#define OUTD 10

typedef __attribute__((ext_vector_type(8))) short bf16x8;
typedef __attribute__((ext_vector_type(4))) float f32x4;
typedef __attribute__((ext_vector_type(4))) unsigned short u16x4;
typedef __attribute__((ext_vector_type(8))) unsigned short u16x8;

__device__ __forceinline__ float b2f(unsigned short u) {
  union { unsigned int i; float f; } c;
  c.i = ((unsigned int)u) << 16;
  return c.f;
}
__device__ __forceinline__ unsigned short f2b(float f) {
  union { float f; unsigned int i; } c;
  c.f = f;
  unsigned int x = c.i + 0x7FFFu + ((c.i >> 16) & 1u);  // RNE
  return (unsigned short)(x >> 16);
}

__device__ __forceinline__ void gload16(const void* g, void* l) {
  __builtin_amdgcn_global_load_lds(
      (const __attribute__((address_space(1))) unsigned int*)g,
      (__attribute__((address_space(3))) unsigned int*)l, 16, 0, 0);
}

// ---------------- CSR build ----------------
__global__ void k_hist(const int* __restrict__ dst, int* __restrict__ deg) {
  int e = blockIdx.x * blockDim.x + threadIdx.x;
  if (e < N_EDGES) atomicAdd(&deg[dst[e]], 1);
}

#define SCAN_NB ((N_NODES + 255) / 256)  // 196

__global__ __launch_bounds__(256) void k_scan1(const int* __restrict__ deg,
                                               int* __restrict__ bsum) {
  int i = blockIdx.x * 256 + threadIdx.x;
  int v = (i < N_NODES) ? deg[i] : 0;
#pragma unroll
  for (int m = 1; m < 64; m <<= 1) v += __shfl_xor(v, m, 64);
  __shared__ int ws[4];
  if ((threadIdx.x & 63) == 0) ws[threadIdx.x >> 6] = v;
  __syncthreads();
  if (threadIdx.x == 0) bsum[blockIdx.x] = ws[0] + ws[1] + ws[2] + ws[3];
}

__global__ __launch_bounds__(256) void k_scan2(const int* __restrict__ bsum,
                                               int* __restrict__ boff) {
  __shared__ int s[256];
  int t = threadIdx.x;
  s[t] = (t < SCAN_NB) ? bsum[t] : 0;
  __syncthreads();
  for (int o = 1; o < 256; o <<= 1) {
    int v = (t >= o) ? s[t - o] : 0;
    __syncthreads();
    s[t] += v;
    __syncthreads();
  }
  if (t < SCAN_NB) boff[t] = (t == 0) ? 0 : s[t - 1];
}

__global__ __launch_bounds__(256) void k_scan3(const int* __restrict__ deg,
                                               const int* __restrict__ boff,
                                               int* __restrict__ rowptr,
                                               int* __restrict__ cursor) {
  __shared__ int s[256];
  int t = threadIdx.x;
  int i = blockIdx.x * 256 + t;
  int v = (i < N_NODES) ? deg[i] : 0;
  s[t] = v;
  __syncthreads();
  for (int o = 1; o < 256; o <<= 1) {
    int w = (t >= o) ? s[t - o] : 0;
    __syncthreads();
    s[t] += w;
    __syncthreads();
  }
  int excl = ((t == 0) ? 0 : s[t - 1]) + boff[blockIdx.x];
  if (i < N_NODES) {
    rowptr[i] = excl;
    cursor[i] = excl;
    if (i == N_NODES - 1) rowptr[N_NODES] = excl + v;
  }
}

__global__ void k_scatter(const int* __restrict__ src, const int* __restrict__ dst,
                          int* __restrict__ cursor, int* __restrict__ csr) {
  int e = blockIdx.x * blockDim.x + threadIdx.x;
  if (e < N_EDGES) {
    int pos = atomicAdd(&cursor[dst[e]], 1);
    csr[pos] = src[e];
  }
}

// ---------------- converts ----------------
__global__ void k_f2b4(const float* __restrict__ in, unsigned short* __restrict__ out,
                       size_t n4) {
  size_t i = ((size_t)blockIdx.x * blockDim.x + threadIdx.x);
  if (i >= n4) return;
  const float4 v = *(const float4*)&in[i * 4];
  u16x4 o = {f2b(v.x), f2b(v.y), f2b(v.z), f2b(v.w)};
  *(u16x4*)&out[i * 4] = o;
}

// W[K][256] f32 -> out[256][K] bf16 (transposed)
__global__ void k_wt(const float* __restrict__ W, unsigned short* __restrict__ out, int K) {
  int o = blockIdx.x * blockDim.x + threadIdx.x;
  if (o >= K * HID) return;
  int c = o / K, k = o - c * K;
  out[o] = f2b(W[(size_t)k * HID + c]);
}

// ---------------- SpMM (pure gather-sum): out[n] = h[n] + sum_{dst=n} h[src] ------
// One wave per node; NG row-streams of RL lanes x 16B; 4-row unroll; shfl-combine.
template <int DIM>
__global__ __launch_bounds__(256) void k_spmm3(const unsigned short* __restrict__ h,
                                               const int* __restrict__ rowptr,
                                               const int* __restrict__ csr,
                                               unsigned short* __restrict__ out) {
  constexpr int RL = DIM / 8;  // lanes per row (16B each)
  constexpr int NG = 64 / RL;  // concurrent row streams per wave
  const int lane = threadIdx.x & 63;
  const int node = blockIdx.x * 4 + (threadIdx.x >> 6);
  const int grp = lane / RL;
  const int cbase = (lane % RL) * 8;
  const int b = rowptr[node], e = rowptr[node + 1];
  const int count = e - b + 1;  // virtual list: [self] + neighbors
  float acc[8] = {};
  int j = grp;
  for (; j + 3 * NG < count; j += 4 * NG) {
    int r0 = (j == 0) ? node : csr[b + j - 1];
    int r1 = csr[b + j + NG - 1];
    int r2 = csr[b + j + 2 * NG - 1];
    int r3 = csr[b + j + 3 * NG - 1];
    u16x8 v0 = *(const u16x8*)(h + (size_t)r0 * DIM + cbase);
    u16x8 v1 = *(const u16x8*)(h + (size_t)r1 * DIM + cbase);
    u16x8 v2 = *(const u16x8*)(h + (size_t)r2 * DIM + cbase);
    u16x8 v3 = *(const u16x8*)(h + (size_t)r3 * DIM + cbase);
#pragma unroll
    for (int q = 0; q < 8; ++q)
      acc[q] += (b2f(v0[q]) + b2f(v1[q])) + (b2f(v2[q]) + b2f(v3[q]));
  }
  for (; j < count; j += NG) {
    int r0 = (j == 0) ? node : csr[b + j - 1];
    u16x8 v0 = *(const u16x8*)(h + (size_t)r0 * DIM + cbase);
#pragma unroll
    for (int q = 0; q < 8; ++q) acc[q] += b2f(v0[q]);
  }
#pragma unroll
  for (int m = RL; m < 64; m <<= 1)
#pragma unroll
    for (int q = 0; q < 8; ++q) acc[q] += __shfl_xor(acc[q], m, 64);
  if (grp == 0) {
    u16x8 o;
#pragma unroll
    for (int q = 0; q < 8; ++q) o[q] = f2b(acc[q]);
    *(u16x8*)(out + (size_t)node * DIM + cbase) = o;
  }
}

// ---------------- MFMA GEMM + fused column stats ----------------
template <int K>
__global__ __launch_bounds__(256) void k_gemm_mfma(const unsigned short* __restrict__ A,
                                                   const unsigned short* __restrict__ Wt,
                                                   const float* __restrict__ bias,
                                                   float* __restrict__ stout,
                                                   unsigned short* __restrict__ C, int M) {
  __shared__ short As[128 * 64];
  __shared__ short Bs[128 * 64];
  __shared__ float s_sum[128], s_sqs[128];
  const int tid = threadIdx.x;
  const int lane = tid & 63;
  const int wv = tid >> 6;
  const int wm = wv >> 1, wn = wv & 1;
  const int l16 = lane & 15, lh = lane >> 4;
  const int rB = blockIdx.x * 128;
  const int cB = blockIdx.y * 128;
  f32x4 acc[4][4] = {};
  if (tid < 128) {
    s_sum[tid] = 0.f;
    s_sqs[tid] = 0.f;
  }

  for (int kt = 0; kt < K / 64; ++kt) {
#pragma unroll
    for (int it = 0; it < 8; ++it) {
      int s = it * 256 + tid;
      if (s < 1024) {
        int r = s >> 3, g = s & 7;
        int gs = g ^ (r & 7);
        int row = rB + r;
        if (row > M - 1) row = M - 1;
        gload16(A + (size_t)row * K + kt * 64 + gs * 8, &As[s * 8]);
      } else {
        int s2 = s - 1024;
        int r = s2 >> 3, g = s2 & 7;
        int gs = g ^ (r & 7);
        gload16(Wt + (size_t)(cB + r) * K + kt * 64 + gs * 8, &Bs[s2 * 8]);
      }
    }
    __syncthreads();
#pragma unroll
    for (int kh = 0; kh < 2; ++kh) {
      bf16x8 af[4], bfr[4];
      const int gsw = (kh * 4 + lh) ^ (l16 & 7);
#pragma unroll
      for (int m = 0; m < 4; ++m) {
        int row = wm * 64 + m * 16 + l16;
        af[m] = *(const bf16x8*)&As[row * 64 + gsw * 8];
      }
#pragma unroll
      for (int n = 0; n < 4; ++n) {
        int col = wn * 64 + n * 16 + l16;
        bfr[n] = *(const bf16x8*)&Bs[col * 64 + gsw * 8];
      }
#pragma unroll
      for (int m = 0; m < 4; ++m)
#pragma unroll
        for (int n = 0; n < 4; ++n)
          acc[m][n] =
              __builtin_amdgcn_mfma_f32_16x16x32_bf16(af[m], bfr[n], acc[m][n], 0, 0, 0);
    }
    __syncthreads();
  }

#pragma unroll
  for (int n = 0; n < 4; ++n) {
    int colL = wn * 64 + n * 16 + l16;
    int col = cB + colL;
    float bv = bias[col];
    float ps = 0.f, pq = 0.f;
#pragma unroll
    for (int m = 0; m < 4; ++m) {
#pragma unroll
      for (int r = 0; r < 4; ++r) {
        int row = rB + wm * 64 + m * 16 + lh * 4 + r;
        if (row < M) {
          float val = acc[m][n][r] + bv;
          ps += val;
          pq += val * val;
          C[(size_t)row * HID + col] = f2b(val);
        }
      }
    }
    atomicAdd(&s_sum[colL], ps);
    atomicAdd(&s_sqs[colL], pq);
  }
  __syncthreads();
  if (tid < 128) {
    atomicAdd(&stout[cB + tid], s_sum[tid]);
    atomicAdd(&stout[HID + cB + tid], s_sqs[tid]);
  }
}

// ---------------- inner BN apply + ReLU (in place, bf16) ----------------
__global__ __launch_bounds__(256) void k_bn_relu_b(unsigned short* __restrict__ X,
                                                   const float* __restrict__ st,
                                                   const float* __restrict__ g,
                                                   const float* __restrict__ b) {
  __shared__ float sc[HID], sh[HID];
  int tid = threadIdx.x;
  {
    const float invM = 1.0f / N_NODES;
    float mean = st[tid] * invM;
    float var = st[HID + tid] * invM - mean * mean;
    float s = g[tid] * rsqrtf(var + 1e-5f);
    sc[tid] = s;
    sh[tid] = b[tid] - mean * s;
  }
  __syncthreads();
  size_t i8 = ((size_t)blockIdx.x * 256 + tid) * 8;
  u16x8 v = *(const u16x8*)&X[i8];
  int c0 = (int)(i8 & (HID - 1));
  u16x8 o;
#pragma unroll
  for (int j = 0; j < 8; ++j) {
    float f = b2f(v[j]) * sc[c0 + j] + sh[c0 + j];
    o[j] = f2b(f > 0.f ? f : 0.f);
  }
  *(u16x8*)&X[i8] = o;
}

// ------- pool over relu(bn(raw)) + optional side-output of applied bf16 h ---------
template <bool WRITEAPP>
__global__ __launch_bounds__(256) void k_pool_apply(const unsigned short* __restrict__ H,
                                                    const int* __restrict__ gid,
                                                    const float* __restrict__ st,
                                                    const float* __restrict__ g,
                                                    const float* __restrict__ bb,
                                                    float* __restrict__ gp,
                                                    unsigned short* __restrict__ happ) {
  const int lane = threadIdx.x & 63;
  const int wv = threadIdx.x >> 6;
  const int grp = lane >> 5;
  const int cbase = (lane & 31) * 8;
  float sc[8], sh[8];
  {
    const float invM = 1.0f / N_NODES;
#pragma unroll
    for (int q = 0; q < 8; ++q) {
      int c = cbase + q;
      float mean = st[c] * invM;
      float var = st[HID + c] * invM - mean * mean;
      float s = g[c] * rsqrtf(var + 1e-5f);
      sc[q] = s;
      sh[q] = bb[c] - mean * s;
    }
  }
  int base = blockIdx.x * 256 + wv * 64 + grp;
  int end = blockIdx.x * 256 + wv * 64 + 64;
  if (end > N_NODES) end = N_NODES;
  float acc[8] = {};
  int cur = -1;
  for (int r = base; r < end; r += 2) {
    int gg = gid[r];
    if (gg != cur) {
      if (cur >= 0) {
#pragma unroll
        for (int q = 0; q < 8; ++q) {
          atomicAdd(&gp[(size_t)cur * HID + cbase + q], acc[q]);
          acc[q] = 0.f;
        }
      }
      cur = gg;
    }
    u16x8 v = *(const u16x8*)(H + (size_t)r * HID + cbase);
    u16x8 o;
#pragma unroll
    for (int q = 0; q < 8; ++q) {
      float f = b2f(v[q]) * sc[q] + sh[q];
      f = f > 0.f ? f : 0.f;
      acc[q] += f;
      if constexpr (WRITEAPP) o[q] = f2b(f);
    }
    if constexpr (WRITEAPP) *(u16x8*)(happ + (size_t)r * HID + cbase) = o;
  }
  if (cur >= 0) {
#pragma unroll
    for (int q = 0; q < 8; ++q) atomicAdd(&gp[(size_t)cur * HID + cbase + q], acc[q]);
  }
}

// pool of raw f32 x [N][128]
__global__ __launch_bounds__(256) void k_pool_x(const float* __restrict__ X,
                                                const int* __restrict__ gid,
                                                float* __restrict__ gp) {
  const int lane = threadIdx.x & 63;
  const int wv = threadIdx.x >> 6;
  const int grp = lane >> 5;
  const int cbase = (lane & 31) * 4;
  int base = blockIdx.x * 256 + wv * 64 + grp;
  int end = blockIdx.x * 256 + wv * 64 + 64;
  if (end > N_NODES) end = N_NODES;
  float acc[4] = {};
  int cur = -1;
  for (int r = base; r < end; r += 2) {
    int gg = gid[r];
    if (gg != cur) {
      if (cur >= 0) {
#pragma unroll
        for (int q = 0; q < 4; ++q) {
          atomicAdd(&gp[(size_t)cur * INDIM + cbase + q], acc[q]);
          acc[q] = 0.f;
        }
      }
      cur = gg;
    }
    float4 v = *(const float4*)(X + (size_t)r * INDIM + cbase);
    acc[0] += v.x;
    acc[1] += v.y;
    acc[2] += v.z;
    acc[3] += v.w;
  }
  if (cur >= 0) {
#pragma unroll
    for (int q = 0; q < 4; ++q) atomicAdd(&gp[(size_t)cur * INDIM + cbase + q], acc[q]);
  }
}

// ---------------- final prediction heads ----------------
__global__ __launch_bounds__(256) void k_score(const float* __restrict__ gp0,
                                               const float* __restrict__ gp,
                                               const float* __restrict__ pw0,
                                               const float* __restrict__ pb0,
                                               const float* __restrict__ pw,
                                               const float* __restrict__ pb,
                                               float* __restrict__ out) {
  __shared__ float red[256];
  int g = blockIdx.x;
  int tid = threadIdx.x;
  for (int o = 0; o < OUTD; ++o) {
    float p = 0.f;
    if (tid < INDIM) p += gp0[g * INDIM + tid] * pw0[tid * OUTD + o];
#pragma unroll
    for (int l = 0; l < 4; ++l)
      p += gp[((size_t)l * N_GRAPHS + g) * HID + tid] * pw[(size_t)(l * HID + tid) * OUTD + o];
    red[tid] = p;
    __syncthreads();
    for (int s = 128; s > 0; s >>= 1) {
      if (tid < s) red[tid] += red[tid + s];
      __syncthreads();
    }
    if (tid == 0) {
      float r = red[0] + pb0[o];
      for (int l = 0; l < 4; ++l) r += pb[l * OUTD + o];
      out[g * OUTD + o] = r;
    }
    __syncthreads();
  }
}

extern "C" void kernel_launch(void* const* d_in, const int* in_sizes, int n_in,
                              void* d_out, int out_size, void* d_ws, size_t ws_size,
                              hipStream_t stream) {
  (void)in_sizes; (void)n_in; (void)out_size; (void)ws_size;
  const float* x = (const float*)d_in[0];
  const float* mlp0_w1 = (const float*)d_in[1];
  const float* mlp0_b1 = (const float*)d_in[2];
  const float* mlp0_bng = (const float*)d_in[3];
  const float* mlp0_bnb = (const float*)d_in[4];
  const float* mlp0_w2 = (const float*)d_in[5];
  const float* mlp0_b2 = (const float*)d_in[6];
  const float* mlps_w1 = (const float*)d_in[7];
  const float* mlps_b1 = (const float*)d_in[8];
  const float* mlps_bng = (const float*)d_in[9];
  const float* mlps_bnb = (const float*)d_in[10];
  const float* mlps_w2 = (const float*)d_in[11];
  const float* mlps_b2 = (const float*)d_in[12];
  const float* bng = (const float*)d_in[13];
  const float* bnb = (const float*)d_in[14];
  const float* pw0 = (const float*)d_in[15];
  const float* pb0 = (const float*)d_in[16];
  const float* pw = (const float*)d_in[17];
  const float* pb = (const float*)d_in[18];
  const int* eidx = (const int*)d_in[19];
  const int* gid = (const int*)d_in[20];
  const int* esrc = eidx;
  const int* edst = eidx + N_EDGES;

  char* w = (char*)d_ws;
  size_t off = 0;
  auto take = [&](size_t bytes) -> void* {
    void* p = w + off;
    off += (bytes + 255) & ~(size_t)255;
    return p;
  };
  unsigned short* xb = (unsigned short*)take((size_t)N_NODES * INDIM * 2);
  unsigned short* P0 = (unsigned short*)take((size_t)N_NODES * HID * 2);
  unsigned short* P1 = (unsigned short*)take((size_t)N_NODES * HID * 2);
  unsigned short* P2 = (unsigned short*)take((size_t)N_NODES * HID * 2);
  unsigned short* wt0_1 = (unsigned short*)take((size_t)HID * INDIM * 2);
  unsigned short* wt0_2 = (unsigned short*)take((size_t)HID * HID * 2);
  unsigned short* wts_1 = (unsigned short*)take((size_t)3 * HID * HID * 2);
  unsigned short* wts_2 = (unsigned short*)take((size_t)3 * HID * HID * 2);
  int* deg = (int*)take((size_t)N_NODES * 4);
  int* rowptr = (int*)take((size_t)(N_NODES + 1) * 4);
  int* cursor = (int*)take((size_t)N_NODES * 4);
  int* csr = (int*)take((size_t)N_EDGES * 4);
  int* bsum = (int*)take((size_t)SCAN_NB * 4);
  int* boff = (int*)take((size_t)(SCAN_NB + 1) * 4);
  float* stats = (float*)take(8 * 512 * 4);
  float* gp0 = (float*)take((size_t)N_GRAPHS * INDIM * 4);
  float* gp = (float*)take((size_t)4 * N_GRAPHS * HID * 4);
  unsigned short* P[3] = {P0, P1, P2};

  hipMemsetAsync(deg, 0, (size_t)N_NODES * 4, stream);
  hipMemsetAsync(stats, 0, 8 * 512 * 4, stream);
  hipMemsetAsync(gp0, 0, (size_t)N_GRAPHS * INDIM * 4, stream);
  hipMemsetAsync(gp, 0, (size_t)4 * N_GRAPHS * HID * 4, stream);

  // prep: converts + weight transposes + CSR
  k_f2b4<<<(N_NODES * INDIM / 4 + 255) / 256, 256, 0, stream>>>(x, xb,
                                                                (size_t)N_NODES * INDIM / 4);
  k_wt<<<(INDIM * HID + 255) / 256, 256, 0, stream>>>(mlp0_w1, wt0_1, INDIM);
  k_wt<<<(HID * HID + 255) / 256, 256, 0, stream>>>(mlp0_w2, wt0_2, HID);
  for (int i = 0; i < 3; ++i) {
    k_wt<<<(HID * HID + 255) / 256, 256, 0, stream>>>(mlps_w1 + (size_t)i * HID * HID,
                                                      wts_1 + (size_t)i * HID * HID, HID);
    k_wt<<<(HID * HID + 255) / 256, 256, 0, stream>>>(mlps_w2 + (size_t)i * HID * HID,
                                                      wts_2 + (size_t)i * HID * HID, HID);
  }
  k_hist<<<(N_EDGES + 255) / 256, 256, 0, stream>>>(edst, deg);
  k_scan1<<<SCAN_NB, 256, 0, stream>>>(deg, bsum);
  k_scan2<<<1, 256, 0, stream>>>(bsum, boff);
  k_scan3<<<SCAN_NB, 256, 0, stream>>>(deg, boff, rowptr, cursor);
  k_scatter<<<(N_EDGES + 255) / 256, 256, 0, stream>>>(esrc, edst, cursor, csr);

  dim3 gemmGrid((N_NODES + 127) / 128, 2);
  const int bnGrid = N_NODES * HID / (256 * 8);  // 6250, exact
  const int poolGrid = (N_NODES + 255) / 256;
  const int spmmGrid = (N_NODES + 3) / 4;

  // pool input representation (hidden_rep[0] = x, f32)
  k_pool_x<<<poolGrid, 256, 0, stream>>>(x, gid, gp0);

  // Per layer l (buffer rotation): AGG=P[l%3], T1=P[(l+1)%3], RAW=P[(l+2)%3],
  // h_app written back into P[l%3]; spmm input for layer l>=1 is P[(l+2)%3].
  for (int l = 0; l < 4; ++l) {
    unsigned short* AGG = P[l % 3];
    unsigned short* T1 = P[(l + 1) % 3];
    unsigned short* RAW = P[(l + 2) % 3];
    float* st1 = stats + (size_t)(2 * l) * 512;
    float* st2 = stats + (size_t)(2 * l + 1) * 512;
    if (l == 0) {
      k_spmm3<INDIM><<<spmmGrid, 256, 0, stream>>>(xb, rowptr, csr, AGG);
      k_gemm_mfma<INDIM><<<gemmGrid, 256, 0, stream>>>(AGG, wt0_1, mlp0_b1, st1, T1,
                                                       N_NODES);
      k_bn_relu_b<<<bnGrid, 256, 0, stream>>>(T1, st1, mlp0_bng, mlp0_bnb);
      k_gemm_mfma<HID><<<gemmGrid, 256, 0, stream>>>(T1, wt0_2, mlp0_b2, st2, RAW, N_NODES);
    } else {
      int li = l - 1;
      k_spmm3<HID><<<spmmGrid, 256, 0, stream>>>(P[(l + 2) % 3], rowptr, csr, AGG);
      k_gemm_mfma<HID><<<gemmGrid, 256, 0, stream>>>(AGG, wts_1 + (size_t)li * HID * HID,
                                                     mlps_b1 + li * HID, st1, T1, N_NODES);
      k_bn_relu_b<<<bnGrid, 256, 0, stream>>>(T1, st1, mlps_bng + li * HID,
                                              mlps_bnb + li * HID);
      k_gemm_mfma<HID><<<gemmGrid, 256, 0, stream>>>(T1, wts_2 + (size_t)li * HID * HID,
                                                     mlps_b2 + li * HID, st2, RAW, N_NODES);
    }
    if (l < 3) {
      k_pool_apply<true><<<poolGrid, 256, 0, stream>>>(RAW, gid, st2, bng + l * HID,
                                                       bnb + l * HID,
                                                       gp + (size_t)l * N_GRAPHS * HID,
                                                       P[l % 3]);
    } else {
      k_pool_apply<false><<<poolGrid, 256, 0, stream>>>(RAW, gid, st2, bng + l * HID,
                                                        bnb + l * HID,
                                                        gp + (size_t)l * N_GRAPHS * HID,
                                                        nullptr);
    }
  }

  k_score<<<N_GRAPHS, 256, 0, stream>>>(gp0, gp, pw0, pb0, pw, pb, (float*)d_out);
}